// Round 2
// baseline (383.578 us; speedup 1.0000x reference)
//
#include <hip/hip_runtime.h>

// out[i, 0:48]  = x[i, :]
// out[i, 48:96] = sum over edges e with row[e]==i of x[col[e], :]
// x: [N, 48] f32, edge_index: [2, E] int32 (row = ei[0:E], col = ei[E:2E])
// out: [N, 96] f32
//
// Strategy: build CSR by destination row (histogram -> scan -> fill), then
// gather-side aggregation: 12 threads per node (one float4 lane each) loop
// the node's neighbor list, accumulate in registers, write out once.
// Eliminates the 76.8M float atomic RMWs (300 MB write traffic) of the
// scatter approach.

constexpr int D_IN  = 48;   // 12 float4
constexpr int D_OUT = 96;   // 24 float4

// ---------------- CSR build ----------------

__global__ void zero_ints_kernel(int* __restrict__ p, int n) {
    int i = blockIdx.x * blockDim.x + threadIdx.x;
    if (i < n) p[i] = 0;
}

__global__ void hist_kernel(const int* __restrict__ row,
                            int* __restrict__ counts, int n_edges) {
    int e = blockIdx.x * blockDim.x + threadIdx.x;
    if (e < n_edges) atomicAdd(&counts[row[e]], 1);
}

// Single-block exclusive scan: counts[0..n) -> offsets[0..n], offsets[n]=total.
__global__ __launch_bounds__(1024)
void scan_kernel(const int* __restrict__ counts,
                 int* __restrict__ offsets, int n) {
    __shared__ int part[1024];
    int t = threadIdx.x;
    int chunk = (n + 1023) / 1024;
    int beg = t * chunk;
    int end = beg + chunk; if (end > n) end = n;
    int s = 0;
    for (int i = beg; i < end; ++i) s += counts[i];
    part[t] = s;
    __syncthreads();
    // Hillis-Steele inclusive scan over 1024 partials
    for (int off = 1; off < 1024; off <<= 1) {
        int v = (t >= off) ? part[t - off] : 0;
        __syncthreads();
        part[t] += v;
        __syncthreads();
    }
    int run = (t == 0) ? 0 : part[t - 1];  // exclusive prefix of this chunk
    for (int i = beg; i < end; ++i) { offsets[i] = run; run += counts[i]; }
    if (t == 1023) offsets[n] = run;  // t=1023's chunk is empty -> run = grand total
}

__global__ void fill_kernel(const int* __restrict__ row,
                            const int* __restrict__ col,
                            const int* __restrict__ offsets,
                            int* __restrict__ cursor,
                            int* __restrict__ sorted_col, int n_edges) {
    int e = blockIdx.x * blockDim.x + threadIdx.x;
    if (e >= n_edges) return;
    int r = row[e];
    int pos = offsets[r] + atomicAdd(&cursor[r], 1);
    sorted_col[pos] = col[e];
}

// ---------------- aggregation ----------------

// 12 threads per node; thread q owns float4 lane q of the node's row.
// Fuses the out[:, :48] = x copy.
__global__ void aggregate_kernel(const float4* __restrict__ x4,
                                 const int* __restrict__ offsets,
                                 const int* __restrict__ sorted_col,
                                 float4* __restrict__ out4, int n_nodes) {
    int gid = blockIdx.x * blockDim.x + threadIdx.x;
    int total = n_nodes * 12;
    if (gid >= total) return;
    int i = gid / 12;
    int q = gid - i * 12;
    int beg = offsets[i];
    int end = offsets[i + 1];
    float4 acc = make_float4(0.f, 0.f, 0.f, 0.f);
    for (int k = beg; k < end; ++k) {
        int c = sorted_col[k];                 // broadcast across the 12 lanes
        float4 v = x4[(long long)c * 12 + q];  // coalesced 192B per node
        acc.x += v.x; acc.y += v.y; acc.z += v.z; acc.w += v.w;
    }
    out4[i * 24 + 12 + q] = acc;
    out4[i * 24 + q]      = x4[i * 12 + q];
}

// ---------------- fallback (round-1 atomic path) ----------------

__global__ void init_out_kernel(const float4* __restrict__ x4,
                                float4* __restrict__ out4, int n_nodes) {
    int idx = blockIdx.x * blockDim.x + threadIdx.x;
    int total = n_nodes * 24;
    if (idx >= total) return;
    int i = idx / 24;
    int q = idx - i * 24;
    out4[idx] = (q < 12) ? x4[i * 12 + q] : make_float4(0.f, 0.f, 0.f, 0.f);
}

__global__ void scatter_add_kernel(const float* __restrict__ x,
                                   const int* __restrict__ row,
                                   const int* __restrict__ col,
                                   float* __restrict__ out, int n_edges) {
    long long gid = (long long)blockIdx.x * blockDim.x + threadIdx.x;
    long long total = (long long)n_edges * D_IN;
    if (gid >= total) return;
    int e = (int)(gid / D_IN);
    int d = (int)(gid - (long long)e * D_IN);
    atomicAdd(out + (long long)row[e] * D_OUT + D_IN + d,
              x[(long long)col[e] * D_IN + d]);
}

// ---------------- launch ----------------

extern "C" void kernel_launch(void* const* d_in, const int* in_sizes, int n_in,
                              void* d_out, int out_size, void* d_ws, size_t ws_size,
                              hipStream_t stream) {
    const float* x  = (const float*)d_in[0];
    const int*   ei = (const int*)d_in[1];
    float*       out = (float*)d_out;

    int n_nodes = in_sizes[0] / D_IN;   // 100000
    int n_edges = in_sizes[1] / 2;      // 1600000
    const int* row = ei;
    const int* col = ei + n_edges;

    // workspace layout (ints): counts[N] | cursor[N] | offsets[N+1] | sorted_col[E]
    size_t needed = ((size_t)2 * n_nodes + (n_nodes + 1) + n_edges) * sizeof(int);

    if (ws_size < needed) {
        // fallback: atomic scatter (known-correct round-1 path)
        int init_total = n_nodes * 24;
        init_out_kernel<<<(init_total + 255) / 256, 256, 0, stream>>>(
            (const float4*)x, (float4*)out, n_nodes);
        long long total = (long long)n_edges * D_IN;
        scatter_add_kernel<<<(int)((total + 255) / 256), 256, 0, stream>>>(
            x, row, col, out, n_edges);
        return;
    }

    int* counts     = (int*)d_ws;
    int* cursor     = counts + n_nodes;
    int* offsets    = cursor + n_nodes;
    int* sorted_col = offsets + (n_nodes + 1);

    // 1) zero counts + cursor (adjacent -> one launch)
    int nz = 2 * n_nodes;
    zero_ints_kernel<<<(nz + 255) / 256, 256, 0, stream>>>(counts, nz);

    // 2) histogram of destination rows
    hist_kernel<<<(n_edges + 255) / 256, 256, 0, stream>>>(row, counts, n_edges);

    // 3) exclusive scan -> offsets
    scan_kernel<<<1, 1024, 0, stream>>>(counts, offsets, n_nodes);

    // 4) bucket-fill sorted_col
    fill_kernel<<<(n_edges + 255) / 256, 256, 0, stream>>>(
        row, col, offsets, cursor, sorted_col, n_edges);

    // 5) gather-side aggregate + fused x copy
    int agg_total = n_nodes * 12;
    aggregate_kernel<<<(agg_total + 255) / 256, 256, 0, stream>>>(
        (const float4*)x, offsets, sorted_col, (float4*)out, n_nodes);
}

// Round 3
// 274.569 us; speedup vs baseline: 1.3970x; 1.3970x over previous
//
#include <hip/hip_runtime.h>

// out[i, 0:48]  = x[i, :]
// out[i, 48:96] = sum over edges e with row[e]==i of x[col[e], :]
// x: [N, 48] f32, edge_index: [2, E] int32 (row = ei[0:E], col = ei[E:2E])
// out: [N, 96] f32
//
// CSR build (histogram -> hierarchical scan -> bucket fill) + gather-side
// aggregation (12 threads/node, register accumulate, single output write).
// Round-2 fix: single-block scan (164 us!) -> 3-kernel hierarchical scan.

constexpr int D_IN  = 48;   // 12 float4
constexpr int D_OUT = 96;   // 24 float4

constexpr int SCAN_TILE = 1024;  // elements per block in the hierarchical scan
constexpr int SCAN_THREADS = 256;
constexpr int SCAN_ITEMS = 4;    // SCAN_THREADS * SCAN_ITEMS == SCAN_TILE

// ---------------- CSR build ----------------

__global__ void zero_ints_kernel(int* __restrict__ p, int n) {
    int i = blockIdx.x * blockDim.x + threadIdx.x;
    if (i < n) p[i] = 0;
}

__global__ void hist_kernel(const int* __restrict__ row,
                            int* __restrict__ counts, int n_edges) {
    int e = blockIdx.x * blockDim.x + threadIdx.x;
    if (e < n_edges) atomicAdd(&counts[row[e]], 1);
}

// Phase 1: per-block sums of counts.
__global__ __launch_bounds__(SCAN_THREADS)
void scan_partial_kernel(const int* __restrict__ counts,
                         int* __restrict__ blk_sums, int n) {
    __shared__ int red[SCAN_THREADS];
    int b = blockIdx.x, t = threadIdx.x;
    int base = b * SCAN_TILE + t * SCAN_ITEMS;
    int s = 0;
#pragma unroll
    for (int j = 0; j < SCAN_ITEMS; ++j) {
        int i = base + j;
        if (i < n) s += counts[i];
    }
    red[t] = s;
    __syncthreads();
    for (int off = SCAN_THREADS / 2; off > 0; off >>= 1) {
        if (t < off) red[t] += red[t + off];
        __syncthreads();
    }
    if (t == 0) blk_sums[b] = red[0];
}

// Phase 2: single small block scans the block sums (nb <= 1024),
// writes exclusive block offsets, and sets offsets[n] = total edge count.
__global__ __launch_bounds__(1024)
void scan_blocks_kernel(const int* __restrict__ blk_sums,
                        int* __restrict__ blk_offs, int nb,
                        int* __restrict__ offsets_end, int total) {
    __shared__ int part[1024];
    int t = threadIdx.x;
    part[t] = (t < nb) ? blk_sums[t] : 0;
    __syncthreads();
    for (int off = 1; off < 1024; off <<= 1) {
        int v = (t >= off) ? part[t - off] : 0;
        __syncthreads();
        part[t] += v;
        __syncthreads();
    }
    if (t < nb) blk_offs[t] = (t == 0) ? 0 : part[t - 1];
    if (t == 0) *offsets_end = total;
}

// Phase 3: per-block exclusive scan + base; writes offsets[i] and seeds
// cursor[i] = offsets[i] so fill_kernel can bump cursor directly.
__global__ __launch_bounds__(SCAN_THREADS)
void scan_final_kernel(const int* __restrict__ counts,
                       const int* __restrict__ blk_offs,
                       int* __restrict__ offsets,
                       int* __restrict__ cursor, int n) {
    __shared__ int part[SCAN_THREADS];
    int b = blockIdx.x, t = threadIdx.x;
    int base = b * SCAN_TILE + t * SCAN_ITEMS;
    int vals[SCAN_ITEMS];
    int s = 0;
#pragma unroll
    for (int j = 0; j < SCAN_ITEMS; ++j) {
        int i = base + j;
        vals[j] = (i < n) ? counts[i] : 0;
        s += vals[j];
    }
    part[t] = s;
    __syncthreads();
    for (int off = 1; off < SCAN_THREADS; off <<= 1) {
        int v = (t >= off) ? part[t - off] : 0;
        __syncthreads();
        part[t] += v;
        __syncthreads();
    }
    int run = blk_offs[b] + ((t == 0) ? 0 : part[t - 1]);
#pragma unroll
    for (int j = 0; j < SCAN_ITEMS; ++j) {
        int i = base + j;
        if (i < n) {
            offsets[i] = run;
            cursor[i] = run;
            run += vals[j];
        }
    }
}

__global__ void fill_kernel(const int* __restrict__ row,
                            const int* __restrict__ col,
                            int* __restrict__ cursor,
                            int* __restrict__ sorted_col, int n_edges) {
    int e = blockIdx.x * blockDim.x + threadIdx.x;
    if (e >= n_edges) return;
    int pos = atomicAdd(&cursor[row[e]], 1);
    sorted_col[pos] = col[e];
}

// ---------------- aggregation ----------------

// 12 threads per node; thread q owns float4 lane q of the node's row.
// Fuses the out[:, :48] = x copy.
__global__ void aggregate_kernel(const float4* __restrict__ x4,
                                 const int* __restrict__ offsets,
                                 const int* __restrict__ sorted_col,
                                 float4* __restrict__ out4, int n_nodes) {
    int gid = blockIdx.x * blockDim.x + threadIdx.x;
    int total = n_nodes * 12;
    if (gid >= total) return;
    int i = gid / 12;
    int q = gid - i * 12;
    int beg = offsets[i];
    int end = offsets[i + 1];
    float4 acc = make_float4(0.f, 0.f, 0.f, 0.f);
    for (int k = beg; k < end; ++k) {
        int c = sorted_col[k];                 // broadcast across the 12 lanes
        float4 v = x4[(long long)c * 12 + q];  // coalesced 192B per node
        acc.x += v.x; acc.y += v.y; acc.z += v.z; acc.w += v.w;
    }
    out4[i * 24 + 12 + q] = acc;
    out4[i * 24 + q]      = x4[i * 12 + q];
}

// ---------------- fallback (round-1 atomic path) ----------------

__global__ void init_out_kernel(const float4* __restrict__ x4,
                                float4* __restrict__ out4, int n_nodes) {
    int idx = blockIdx.x * blockDim.x + threadIdx.x;
    int total = n_nodes * 24;
    if (idx >= total) return;
    int i = idx / 24;
    int q = idx - i * 24;
    out4[idx] = (q < 12) ? x4[i * 12 + q] : make_float4(0.f, 0.f, 0.f, 0.f);
}

__global__ void scatter_add_kernel(const float* __restrict__ x,
                                   const int* __restrict__ row,
                                   const int* __restrict__ col,
                                   float* __restrict__ out, int n_edges) {
    long long gid = (long long)blockIdx.x * blockDim.x + threadIdx.x;
    long long total = (long long)n_edges * D_IN;
    if (gid >= total) return;
    int e = (int)(gid / D_IN);
    int d = (int)(gid - (long long)e * D_IN);
    atomicAdd(out + (long long)row[e] * D_OUT + D_IN + d,
              x[(long long)col[e] * D_IN + d]);
}

// ---------------- launch ----------------

extern "C" void kernel_launch(void* const* d_in, const int* in_sizes, int n_in,
                              void* d_out, int out_size, void* d_ws, size_t ws_size,
                              hipStream_t stream) {
    const float* x  = (const float*)d_in[0];
    const int*   ei = (const int*)d_in[1];
    float*       out = (float*)d_out;

    int n_nodes = in_sizes[0] / D_IN;   // 100000
    int n_edges = in_sizes[1] / 2;      // 1600000
    const int* row = ei;
    const int* col = ei + n_edges;

    int n_blocks = (n_nodes + SCAN_TILE - 1) / SCAN_TILE;  // 98 for N=100000

    // workspace (ints): counts[N] | cursor[N] | offsets[N+1] |
    //                   blk_sums[nb] | blk_offs[nb] | sorted_col[E]
    size_t needed = ((size_t)2 * n_nodes + (n_nodes + 1) +
                     2 * (size_t)n_blocks + n_edges) * sizeof(int);

    if (ws_size < needed || n_blocks > 1024) {
        // fallback: atomic scatter (known-correct round-1 path)
        int init_total = n_nodes * 24;
        init_out_kernel<<<(init_total + 255) / 256, 256, 0, stream>>>(
            (const float4*)x, (float4*)out, n_nodes);
        long long total = (long long)n_edges * D_IN;
        scatter_add_kernel<<<(int)((total + 255) / 256), 256, 0, stream>>>(
            x, row, col, out, n_edges);
        return;
    }

    int* counts     = (int*)d_ws;
    int* cursor     = counts + n_nodes;
    int* offsets    = cursor + n_nodes;
    int* blk_sums   = offsets + (n_nodes + 1);
    int* blk_offs   = blk_sums + n_blocks;
    int* sorted_col = blk_offs + n_blocks;

    // 1) zero counts
    zero_ints_kernel<<<(n_nodes + 255) / 256, 256, 0, stream>>>(counts, n_nodes);

    // 2) histogram of destination rows
    hist_kernel<<<(n_edges + 255) / 256, 256, 0, stream>>>(row, counts, n_edges);

    // 3) hierarchical exclusive scan -> offsets (and cursor = offsets)
    scan_partial_kernel<<<n_blocks, SCAN_THREADS, 0, stream>>>(
        counts, blk_sums, n_nodes);
    scan_blocks_kernel<<<1, 1024, 0, stream>>>(
        blk_sums, blk_offs, n_blocks, offsets + n_nodes, n_edges);
    scan_final_kernel<<<n_blocks, SCAN_THREADS, 0, stream>>>(
        counts, blk_offs, offsets, cursor, n_nodes);

    // 4) bucket-fill sorted_col
    fill_kernel<<<(n_edges + 255) / 256, 256, 0, stream>>>(
        row, col, cursor, sorted_col, n_edges);

    // 5) gather-side aggregate + fused x copy
    int agg_total = n_nodes * 12;
    aggregate_kernel<<<(agg_total + 255) / 256, 256, 0, stream>>>(
        (const float4*)x, offsets, sorted_col, (float4*)out, n_nodes);
}